// Round 9
// baseline (162.283 us; speedup 1.0000x reference)
//
#include <hip/hip_runtime.h>
#include <hip/hip_bf16.h>

#define N_ROWS 8192
#define DIM 1024
#define TEMP_INV (1.0f / 0.07f)
#define LOG2E 1.4426950408889634f
#define LN2 0.6931471805599453f

typedef __attribute__((ext_vector_type(4))) int i32x4;

__device__ inline void gload_lds16(const void* g, void* l) {
    __builtin_amdgcn_global_load_lds(
        (const __attribute__((address_space(1))) void*)g,
        (__attribute__((address_space(3))) void*)l,
        16, 0, 0);
}

// ------- Kernel 1: L2-normalize rows, quantize to int8 + per-row scale ----
// Also zeroes S1/S2/CNT (replaces the separate memset dispatch).
__global__ __launch_bounds__(256) void knorm(const float* __restrict__ X,
                                             char* __restrict__ Q,
                                             float* __restrict__ SC,
                                             float* __restrict__ S1,
                                             float* __restrict__ S2,
                                             float* __restrict__ CNT) {
    const int row = blockIdx.x;
    const int t = threadIdx.x;
    const float* x = X + (size_t)row * DIM;
    float4 v = reinterpret_cast<const float4*>(x)[t];
    float ss = v.x * v.x + v.y * v.y + v.z * v.z + v.w * v.w;
    float mx = fmaxf(fmaxf(fabsf(v.x), fabsf(v.y)), fmaxf(fabsf(v.z), fabsf(v.w)));
    #pragma unroll
    for (int off = 32; off > 0; off >>= 1) {
        ss += __shfl_down(ss, off);
        mx = fmaxf(mx, __shfl_down(mx, off));
    }
    __shared__ float redS[4], redM[4];
    if ((t & 63) == 0) { redS[t >> 6] = ss; redM[t >> 6] = mx; }
    __syncthreads();
    float tot = redS[0] + redS[1] + redS[2] + redS[3];
    float amax = fmaxf(fmaxf(redM[0], redM[1]), fmaxf(redM[2], redM[3]));
    amax = fmaxf(amax, 1e-20f);
    const float norm = fmaxf(sqrtf(tot), 1e-12f);
    const float qmul = 127.0f / amax;                 // x -> q
    const float scale = amax / (127.0f * norm);       // q -> f
    int q0 = (int)rintf(v.x * qmul);
    int q1 = (int)rintf(v.y * qmul);
    int q2 = (int)rintf(v.z * qmul);
    int q3 = (int)rintf(v.w * qmul);
    q0 = min(max(q0, -127), 127); q1 = min(max(q1, -127), 127);
    q2 = min(max(q2, -127), 127); q3 = min(max(q3, -127), 127);
    const unsigned packed = (unsigned)(q0 & 0xff) | ((unsigned)(q1 & 0xff) << 8) |
                            ((unsigned)(q2 & 0xff) << 16) | ((unsigned)(q3 & 0xff) << 24);
    reinterpret_cast<unsigned*>(Q + (size_t)row * DIM)[t] = packed;
    if (t == 0) SC[row] = scale;
    if (t == 1) { S1[row] = 0.f; S2[row] = 0.f; CNT[row] = 0.f; }
}

// ------- Kernel 2: fused int8 GEMM (q q^T) + streaming reductions ---------
// Proven r5 shell: 128x128 tile, BK=128 (8 K-iters), single-buffer LDS,
// 4 waves (2x2), per-wave 64x64 via 4x4 fragments of mfma_i32_16x16x64_i8,
// XOR-swizzle (byte ^= (row&7)<<4) via pre-swizzled global source.
// Changes vs r5: labels/scales NOT in LDS (epilogue reads them from global,
// 16-lane broadcast, L2-hot) -> LDS exactly 32 KB -> 5 blocks/CU
// (__launch_bounds__(256,5)); exp2-prefolded scales save 1 v_mul/element.
__global__ __launch_bounds__(256, 5) void kgemm(const char* __restrict__ Q,
                                                const float* __restrict__ SC,
                                                const int* __restrict__ labels,
                                                float* __restrict__ S1,
                                                float* __restrict__ S2,
                                                float* __restrict__ CNT) {
    constexpr int BM = 128, BK = 128;
    __shared__ __align__(16) char As[BM * BK];
    __shared__ __align__(16) char Bs[BM * BK];

    // XCD chunk swizzle (2080 = 8 * 260, bijective), then triangular decode
    const int bid0 = blockIdx.x;
    const int bid = (bid0 & 7) * 260 + (bid0 >> 3);
    int a = (int)((sqrtf(8.0f * (float)bid + 1.0f) - 1.0f) * 0.5f);
    while ((a + 1) * (a + 2) / 2 <= bid) ++a;
    while (a * (a + 1) / 2 > bid) --a;
    const int bx = a;
    const int by = bid - a * (a + 1) / 2;
    const bool diag = (bx == by);
    const int rowBase = by * BM;
    const int colBase = bx * BM;

    const int t = threadIdx.x;
    const int lane = t & 63;
    const int wid = t >> 6;
    const int wr = wid >> 1;
    const int wc = wid & 1;
    const int l16 = lane & 15;
    const int g16 = lane >> 4;

    i32x4 acc[4][4];
    #pragma unroll
    for (int m = 0; m < 4; ++m)
        #pragma unroll
        for (int n = 0; n < 4; ++n)
            acc[m][n] = i32x4{0, 0, 0, 0};

    const int srow = t >> 3;            // 0..31
    const int scolL = (t & 7) * 16;     // linear LDS byte col in [0,128)
    const int xorb = (l16 & 7) << 4;    // read-side swizzle

    for (int kt = 0; kt < DIM / BK; ++kt) {
        const int k0 = kt * BK;
        #pragma unroll
        for (int i = 0; i < 4; ++i) {
            const int r = i * 32 + srow;
            const int sg = scolL ^ ((r & 7) << 4);  // inverse-swizzled source col
            gload_lds16(Q + (size_t)(rowBase + r) * DIM + k0 + sg, &As[r * BK + scolL]);
            gload_lds16(Q + (size_t)(colBase + r) * DIM + k0 + sg, &Bs[r * BK + scolL]);
        }
        __syncthreads();

        #pragma unroll
        for (int kk = 0; kk < 2; ++kk) {
            const int ck = (kk * 64 + g16 * 16) ^ xorb;
            i32x4 av[4], bv[4];
            #pragma unroll
            for (int m = 0; m < 4; ++m)
                av[m] = *reinterpret_cast<const i32x4*>(&As[(wr * 64 + m * 16 + l16) * BK + ck]);
            #pragma unroll
            for (int n = 0; n < 4; ++n)
                bv[n] = *reinterpret_cast<const i32x4*>(&Bs[(wc * 64 + n * 16 + l16) * BK + ck]);
            #pragma unroll
            for (int m = 0; m < 4; ++m)
                #pragma unroll
                for (int n = 0; n < 4; ++n)
                    acc[m][n] = __builtin_amdgcn_mfma_i32_16x16x64_i8(av[m], bv[n], acc[m][n], 0, 0, 0);
        }
        __syncthreads();
    }

    // Epilogue. C/D layout (dtype-independent):
    //   col = colBase + wc*64 + n*16 + l16 ; row = rowBase + wr*64 + m*16 + g16*4 + reg
    // Labels/scales read directly from global (L2-hot; 16-lane broadcast).
    int labCn[4];
    float scCl2[4];   // SC[col] * TEMP_INV * LOG2E  (exp2-prefolded)
    #pragma unroll
    for (int n = 0; n < 4; ++n) {
        const int c = colBase + wc * 64 + n * 16 + l16;
        labCn[n] = labels[c];
        scCl2[n] = SC[c] * (TEMP_INV * LOG2E);
    }

    const unsigned long long grpmask = 0xFFFFull << (g16 * 16);

    float colE[4]  = {0.f, 0.f, 0.f, 0.f};
    float colS2[4] = {0.f, 0.f, 0.f, 0.f};
    float colC[4]  = {0.f, 0.f, 0.f, 0.f};

    #pragma unroll
    for (int m = 0; m < 4; ++m) {
        const int rloc = wr * 64 + m * 16 + g16 * 4;
        #pragma unroll
        for (int reg = 0; reg < 4; ++reg) {
            const int row = rowBase + rloc + reg;
            const int labRow = labels[row];
            const float sRow = SC[row];
            float e = 0.f, s2 = 0.f, c = 0.f;
            #pragma unroll
            for (int n = 0; n < 4; ++n) {
                // arg2 = sim * log2(e); exp(sim) == exp2(arg2)
                const float arg2 = (float)acc[m][n][reg] * sRow * scCl2[n];
                const int col = colBase + wc * 64 + n * 16 + l16;
                const float ex = __builtin_amdgcn_exp2f(arg2);
                const bool same = (labRow == labCn[n]);
                if (diag) {
                    if (row != col) e += ex;
                } else {
                    e += ex;
                    colE[n] += ex;
                }
                if (same) {
                    const float sim = arg2 * LN2;
                    s2 += sim; c += 1.0f;
                    if (!diag) { colS2[n] += sim; colC[n] += 1.0f; }
                }
            }
            // e always reduced; s2/cnt only if any lane in this 16-group matched
            const unsigned long long bal = __ballot(c != 0.f);
            const bool doS = (bal & grpmask) != 0ull;
            #pragma unroll
            for (int off = 1; off < 16; off <<= 1) e += __shfl_xor(e, off);
            if (doS) {
                #pragma unroll
                for (int off = 1; off < 16; off <<= 1) {
                    s2 += __shfl_xor(s2, off);
                    c  += __shfl_xor(c, off);
                }
            }
            if (l16 == 0) {
                atomicAdd(&S1[row], e);
                if (doS) {
                    atomicAdd(&S2[row], s2);
                    atomicAdd(&CNT[row], c);
                }
            }
        }
    }

    // Column-direction reduction for off-diagonal tiles (symmetry).
    if (!diag) {
        #pragma unroll
        for (int n = 0; n < 4; ++n) {
            float ce = colE[n], cs = colS2[n], cc = colC[n];
            const unsigned long long bal = __ballot(cc != 0.f);
            #pragma unroll
            for (int off = 16; off < 64; off <<= 1) ce += __shfl_xor(ce, off);
            if (bal) {
                #pragma unroll
                for (int off = 16; off < 64; off <<= 1) {
                    cs += __shfl_xor(cs, off);
                    cc += __shfl_xor(cc, off);
                }
            }
            if (g16 == 0) {
                const int col = colBase + wc * 64 + n * 16 + l16;
                atomicAdd(&S1[col], ce);
                if (bal) {
                    atomicAdd(&S2[col], cs);
                    atomicAdd(&CNT[col], cc);
                }
            }
        }
    }
}

// ---------------- Kernel 3: finalize ----------------
__global__ __launch_bounds__(1024) void kfinal(const float* __restrict__ S1,
                                               const float* __restrict__ S2,
                                               const float* __restrict__ CNT,
                                               float* __restrict__ out) {
    const int t = threadIdx.x;
    float a = 0.f;
    for (int i = t; i < N_ROWS; i += 1024) {
        const float cnt = CNT[i];
        const float ld = logf(S1[i] + 1e-12f);
        a += (cnt * ld - S2[i]) / (cnt + 1e-12f);
    }
    #pragma unroll
    for (int off = 32; off > 0; off >>= 1) a += __shfl_down(a, off);
    __shared__ float red[16];
    if ((t & 63) == 0) red[t >> 6] = a;
    __syncthreads();
    if (t == 0) {
        float s = 0.f;
        #pragma unroll
        for (int i = 0; i < 16; ++i) s += red[i];
        out[0] = s / (float)N_ROWS;
    }
}

extern "C" void kernel_launch(void* const* d_in, const int* in_sizes, int n_in,
                              void* d_out, int out_size, void* d_ws, size_t ws_size,
                              hipStream_t stream) {
    const float* feat = (const float*)d_in[0];
    const int* labels = (const int*)d_in[1];
    float* out = (float*)d_out;

    char* Q = (char*)d_ws;
    float* SC = (float*)((char*)d_ws + (size_t)N_ROWS * DIM);
    float* S1 = SC + N_ROWS;
    float* S2 = S1 + N_ROWS;
    float* CNT = S2 + N_ROWS;

    constexpr int NT = N_ROWS / 128;              // 64 tiles per dim
    constexpr int NBLK = NT * (NT + 1) / 2;       // 2080 triangular blocks

    knorm<<<N_ROWS, 256, 0, stream>>>(feat, Q, SC, S1, S2, CNT);
    kgemm<<<NBLK, 256, 0, stream>>>(Q, SC, labels, S1, S2, CNT);
    kfinal<<<1, 1024, 0, stream>>>(S1, S2, CNT, out);
}

// Round 10
// 78.052 us; speedup vs baseline: 2.0792x; 2.0792x over previous
//
#include <hip/hip_runtime.h>
#include <hip/hip_bf16.h>

#define N_ROWS 8192
#define DIM 1024
#define TEMP_INV (1.0f / 0.07f)
#define LOG2E 1.4426950408889634f
#define LN2 0.6931471805599453f

typedef __attribute__((ext_vector_type(4))) int i32x4;

__device__ inline void gload_lds16(const void* g, void* l) {
    __builtin_amdgcn_global_load_lds(
        (const __attribute__((address_space(1))) void*)g,
        (__attribute__((address_space(3))) void*)l,
        16, 0, 0);
}

// ------- Kernel 1: L2-normalize rows, quantize to int8 + per-row scale ----
// Also zeroes S1/S2/CNT (replaces the separate memset dispatch).
__global__ __launch_bounds__(256) void knorm(const float* __restrict__ X,
                                             char* __restrict__ Q,
                                             float* __restrict__ SC,
                                             float* __restrict__ S1,
                                             float* __restrict__ S2,
                                             float* __restrict__ CNT) {
    const int row = blockIdx.x;
    const int t = threadIdx.x;
    const float* x = X + (size_t)row * DIM;
    float4 v = reinterpret_cast<const float4*>(x)[t];
    float ss = v.x * v.x + v.y * v.y + v.z * v.z + v.w * v.w;
    float mx = fmaxf(fmaxf(fabsf(v.x), fabsf(v.y)), fmaxf(fabsf(v.z), fabsf(v.w)));
    #pragma unroll
    for (int off = 32; off > 0; off >>= 1) {
        ss += __shfl_down(ss, off);
        mx = fmaxf(mx, __shfl_down(mx, off));
    }
    __shared__ float redS[4], redM[4];
    if ((t & 63) == 0) { redS[t >> 6] = ss; redM[t >> 6] = mx; }
    __syncthreads();
    float tot = redS[0] + redS[1] + redS[2] + redS[3];
    float amax = fmaxf(fmaxf(redM[0], redM[1]), fmaxf(redM[2], redM[3]));
    amax = fmaxf(amax, 1e-20f);
    const float norm = fmaxf(sqrtf(tot), 1e-12f);
    const float qmul = 127.0f / amax;                 // x -> q
    const float scale = amax / (127.0f * norm);       // q -> f
    int q0 = (int)rintf(v.x * qmul);
    int q1 = (int)rintf(v.y * qmul);
    int q2 = (int)rintf(v.z * qmul);
    int q3 = (int)rintf(v.w * qmul);
    q0 = min(max(q0, -127), 127); q1 = min(max(q1, -127), 127);
    q2 = min(max(q2, -127), 127); q3 = min(max(q3, -127), 127);
    const unsigned packed = (unsigned)(q0 & 0xff) | ((unsigned)(q1 & 0xff) << 8) |
                            ((unsigned)(q2 & 0xff) << 16) | ((unsigned)(q3 & 0xff) << 24);
    reinterpret_cast<unsigned*>(Q + (size_t)row * DIM)[t] = packed;
    if (t == 0) SC[row] = scale;
    if (t == 1) { S1[row] = 0.f; S2[row] = 0.f; CNT[row] = 0.f; }
}

// ------- Kernel 2: fused int8 GEMM (q q^T) + streaming reductions ---------
// Proven r5 shell, byte-identical structure: 128x128 tile, BK=128 (8 K-iters),
// single-buffer 32KB LDS + 2KB labels (4 blocks/CU TLP hides the drains),
// 4 waves (2x2), per-wave 64x64 via 4x4 fragments of mfma_i32_16x16x64_i8,
// XOR-swizzle (byte ^= (row&7)<<4) via pre-swizzled global source.
// Micro-pass vs r5: (1) kt loop fully unrolled with precomputed stage base
// addresses -> kt*128 folds into the gload_lds 13-bit offset immediate,
// eliminating per-iter address VALU; (2) exp2-prefolded scales in epilogue.
__global__ __launch_bounds__(256) void kgemm(const char* __restrict__ Q,
                                             const float* __restrict__ SC,
                                             const int* __restrict__ labels,
                                             float* __restrict__ S1,
                                             float* __restrict__ S2,
                                             float* __restrict__ CNT) {
    constexpr int BM = 128, BK = 128;
    __shared__ __align__(16) char As[BM * BK];
    __shared__ __align__(16) char Bs[BM * BK];
    __shared__ int labR[BM];
    __shared__ int labC[BM];
    __shared__ float scR[BM];
    __shared__ float scCs[BM];

    // XCD chunk swizzle (2080 = 8 * 260, bijective), then triangular decode
    const int bid0 = blockIdx.x;
    const int bid = (bid0 & 7) * 260 + (bid0 >> 3);
    int a = (int)((sqrtf(8.0f * (float)bid + 1.0f) - 1.0f) * 0.5f);
    while ((a + 1) * (a + 2) / 2 <= bid) ++a;
    while (a * (a + 1) / 2 > bid) --a;
    const int bx = a;
    const int by = bid - a * (a + 1) / 2;
    const bool diag = (bx == by);
    const int rowBase = by * BM;
    const int colBase = bx * BM;

    const int t = threadIdx.x;
    const int lane = t & 63;
    const int wid = t >> 6;
    const int wr = wid >> 1;
    const int wc = wid & 1;
    const int l16 = lane & 15;
    const int g16 = lane >> 4;

    if (t < 128) { labR[t] = labels[rowBase + t]; scR[t] = SC[rowBase + t]; }
    else {
        labC[t - 128] = labels[colBase + (t - 128)];
        scCs[t - 128] = SC[colBase + (t - 128)] * (TEMP_INV * LOG2E);  // exp2-prefold
    }

    i32x4 acc[4][4];
    #pragma unroll
    for (int m = 0; m < 4; ++m)
        #pragma unroll
        for (int n = 0; n < 4; ++n)
            acc[m][n] = i32x4{0, 0, 0, 0};

    const int srow = t >> 3;            // 0..31
    const int scolL = (t & 7) * 16;     // linear LDS byte col in [0,128)
    const int xorb = (l16 & 7) << 4;    // read-side swizzle

    // precomputed per-thread stage sources (loop-invariant); kt*128 becomes
    // the gload_lds offset immediate after full unroll.
    const char* srcA[4];
    const char* srcB[4];
    int dstOff[4];
    #pragma unroll
    for (int i = 0; i < 4; ++i) {
        const int r = i * 32 + srow;
        const int sg = scolL ^ ((r & 7) << 4);  // inverse-swizzled source col
        srcA[i] = Q + (size_t)(rowBase + r) * DIM + sg;
        srcB[i] = Q + (size_t)(colBase + r) * DIM + sg;
        dstOff[i] = r * BK + scolL;
    }

    #pragma unroll
    for (int kt = 0; kt < DIM / BK; ++kt) {
        const int k0 = kt * BK;
        #pragma unroll
        for (int i = 0; i < 4; ++i) {
            gload_lds16(srcA[i] + k0, &As[dstOff[i]]);
            gload_lds16(srcB[i] + k0, &Bs[dstOff[i]]);
        }
        __syncthreads();

        #pragma unroll
        for (int kk = 0; kk < 2; ++kk) {
            const int ck = (kk * 64 + g16 * 16) ^ xorb;
            i32x4 av[4], bv[4];
            #pragma unroll
            for (int m = 0; m < 4; ++m)
                av[m] = *reinterpret_cast<const i32x4*>(&As[(wr * 64 + m * 16 + l16) * BK + ck]);
            #pragma unroll
            for (int n = 0; n < 4; ++n)
                bv[n] = *reinterpret_cast<const i32x4*>(&Bs[(wc * 64 + n * 16 + l16) * BK + ck]);
            #pragma unroll
            for (int m = 0; m < 4; ++m)
                #pragma unroll
                for (int n = 0; n < 4; ++n)
                    acc[m][n] = __builtin_amdgcn_mfma_i32_16x16x64_i8(av[m], bv[n], acc[m][n], 0, 0, 0);
        }
        __syncthreads();
    }

    // Epilogue. C/D layout (dtype-independent):
    //   col = colBase + wc*64 + n*16 + l16 ; row = rowBase + wr*64 + m*16 + g16*4 + reg
    int labCn[4];
    float scCl2[4];
    #pragma unroll
    for (int n = 0; n < 4; ++n) {
        const int c = wc * 64 + n * 16 + l16;
        labCn[n] = labC[c];
        scCl2[n] = scCs[c];          // already * TEMP_INV * LOG2E
    }

    const unsigned long long grpmask = 0xFFFFull << (g16 * 16);

    float colE[4]  = {0.f, 0.f, 0.f, 0.f};
    float colS2[4] = {0.f, 0.f, 0.f, 0.f};
    float colC[4]  = {0.f, 0.f, 0.f, 0.f};

    #pragma unroll
    for (int m = 0; m < 4; ++m) {
        const int rloc = wr * 64 + m * 16 + g16 * 4;
        #pragma unroll
        for (int reg = 0; reg < 4; ++reg) {
            const int row = rowBase + rloc + reg;
            const int labRow = labR[rloc + reg];
            const float sRow = scR[rloc + reg];
            float e = 0.f, s2 = 0.f, c = 0.f;
            #pragma unroll
            for (int n = 0; n < 4; ++n) {
                // arg2 = sim * log2(e); exp(sim) == exp2(arg2)
                const float arg2 = (float)acc[m][n][reg] * sRow * scCl2[n];
                const int col = colBase + wc * 64 + n * 16 + l16;
                const float ex = __builtin_amdgcn_exp2f(arg2);
                const bool same = (labRow == labCn[n]);
                if (diag) {
                    if (row != col) e += ex;
                } else {
                    e += ex;
                    colE[n] += ex;
                }
                if (same) {
                    const float sim = arg2 * LN2;
                    s2 += sim; c += 1.0f;
                    if (!diag) { colS2[n] += sim; colC[n] += 1.0f; }
                }
            }
            // e always reduced; s2/cnt only if any lane in this 16-group matched
            const unsigned long long bal = __ballot(c != 0.f);
            const bool doS = (bal & grpmask) != 0ull;
            #pragma unroll
            for (int off = 1; off < 16; off <<= 1) e += __shfl_xor(e, off);
            if (doS) {
                #pragma unroll
                for (int off = 1; off < 16; off <<= 1) {
                    s2 += __shfl_xor(s2, off);
                    c  += __shfl_xor(c, off);
                }
            }
            if (l16 == 0) {
                atomicAdd(&S1[row], e);
                if (doS) {
                    atomicAdd(&S2[row], s2);
                    atomicAdd(&CNT[row], c);
                }
            }
        }
    }

    // Column-direction reduction for off-diagonal tiles (symmetry).
    if (!diag) {
        #pragma unroll
        for (int n = 0; n < 4; ++n) {
            float ce = colE[n], cs = colS2[n], cc = colC[n];
            const unsigned long long bal = __ballot(cc != 0.f);
            #pragma unroll
            for (int off = 16; off < 64; off <<= 1) ce += __shfl_xor(ce, off);
            if (bal) {
                #pragma unroll
                for (int off = 16; off < 64; off <<= 1) {
                    cs += __shfl_xor(cs, off);
                    cc += __shfl_xor(cc, off);
                }
            }
            if (g16 == 0) {
                const int col = colBase + wc * 64 + n * 16 + l16;
                atomicAdd(&S1[col], ce);
                if (bal) {
                    atomicAdd(&S2[col], cs);
                    atomicAdd(&CNT[col], cc);
                }
            }
        }
    }
}

// ---------------- Kernel 3: finalize ----------------
__global__ __launch_bounds__(1024) void kfinal(const float* __restrict__ S1,
                                               const float* __restrict__ S2,
                                               const float* __restrict__ CNT,
                                               float* __restrict__ out) {
    const int t = threadIdx.x;
    float a = 0.f;
    for (int i = t; i < N_ROWS; i += 1024) {
        const float cnt = CNT[i];
        const float ld = logf(S1[i] + 1e-12f);
        a += (cnt * ld - S2[i]) / (cnt + 1e-12f);
    }
    #pragma unroll
    for (int off = 32; off > 0; off >>= 1) a += __shfl_down(a, off);
    __shared__ float red[16];
    if ((t & 63) == 0) red[t >> 6] = a;
    __syncthreads();
    if (t == 0) {
        float s = 0.f;
        #pragma unroll
        for (int i = 0; i < 16; ++i) s += red[i];
        out[0] = s / (float)N_ROWS;
    }
}

extern "C" void kernel_launch(void* const* d_in, const int* in_sizes, int n_in,
                              void* d_out, int out_size, void* d_ws, size_t ws_size,
                              hipStream_t stream) {
    const float* feat = (const float*)d_in[0];
    const int* labels = (const int*)d_in[1];
    float* out = (float*)d_out;

    char* Q = (char*)d_ws;
    float* SC = (float*)((char*)d_ws + (size_t)N_ROWS * DIM);
    float* S1 = SC + N_ROWS;
    float* S2 = S1 + N_ROWS;
    float* CNT = S2 + N_ROWS;

    constexpr int NT = N_ROWS / 128;              // 64 tiles per dim
    constexpr int NBLK = NT * (NT + 1) / 2;       // 2080 triangular blocks

    knorm<<<N_ROWS, 256, 0, stream>>>(feat, Q, SC, S1, S2, CNT);
    kgemm<<<NBLK, 256, 0, stream>>>(Q, SC, labels, S1, S2, CNT);
    kfinal<<<1, 1024, 0, stream>>>(S1, S2, CNT, out);
}